// Round 1
// baseline (799.025 us; speedup 1.0000x reference)
//
#include <hip/hip_runtime.h>
#include <stdint.h>

#define NPRIOR   15130
#define BATCH    32
#define NCLS     81
#define NCLS_OUT 80
#define NDET     200
#define CONF_T   0.05f
#define IOU_T    0.5f
#define CAND_CAP 1024
#define NGRP     5
#define GRP      16

// ---------------------------------------------------------------------------
// Kernel 0: zero the per-(b,c) candidate counters (ws is poisoned 0xAA).
// ---------------------------------------------------------------------------
__global__ __launch_bounds__(256) void zero_counters(unsigned int* __restrict__ counters, int n) {
    int i = blockIdx.x * 256 + threadIdx.x;
    if (i < n) counters[i] = 0u;
}

// ---------------------------------------------------------------------------
// Kernel A: per (b, n): decode box to ltrb; softmax over 81 classes;
// scatter candidates with prob > CONF_T into per-(b,c) global lists.
// Exact op order of reference, no FMA contraction (__f*_rn).
// ---------------------------------------------------------------------------
__global__ __launch_bounds__(256) void decode_softmax_scatter(
    const float* __restrict__ bboxes,     // (B,4,N)
    const float* __restrict__ scores,     // (B,81,N)
    const float* __restrict__ scale_xy_p, // (1,)
    const float* __restrict__ scale_wh_p, // (1,)
    const float* __restrict__ dboxes,     // (1,N,4)
    float* __restrict__ boxes_ltrb,       // (B,N,4)
    unsigned int* __restrict__ counters,  // (B*80)
    unsigned long long* __restrict__ cand_g) // (B*80, CAND_CAP)
{
    int b = blockIdx.y;
    int n = blockIdx.x * 256 + threadIdx.x;
    if (n >= NPRIOR) return;

    // ---- decode (ltrb) ----
    float sx = scale_xy_p[0], sw = scale_wh_p[0];
    const float* bb = bboxes + (size_t)b * 4 * NPRIOR + n;
    float bx = bb[0];
    float by = bb[NPRIOR];
    float bw = bb[2 * NPRIOR];
    float bh = bb[3 * NPRIOR];
    float dx = dboxes[n * 4 + 0], dy = dboxes[n * 4 + 1];
    float dw = dboxes[n * 4 + 2], dh = dboxes[n * 4 + 3];
    // xy = (bb * scale_xy) * d_wh + d_xy ; wh = exp(bb * scale_wh) * d_wh
    float x = __fadd_rn(__fmul_rn(__fmul_rn(bx, sx), dw), dx);
    float y = __fadd_rn(__fmul_rn(__fmul_rn(by, sx), dh), dy);
    float w = __fmul_rn(expf(__fmul_rn(bw, sw)), dw);
    float h = __fmul_rn(expf(__fmul_rn(bh, sw)), dh);
    float hw = __fmul_rn(0.5f, w), hh = __fmul_rn(0.5f, h);
    float4 box;
    box.x = __fsub_rn(x, hw);
    box.y = __fsub_rn(y, hh);
    box.z = __fadd_rn(x, hw);
    box.w = __fadd_rn(y, hh);
    ((float4*)boxes_ltrb)[(size_t)b * NPRIOR + n] = box;

    // ---- softmax over 81 classes ----
    const float* sc = scores + (size_t)b * NCLS * NPRIOR + n;
    float v[NCLS];
    float mx = -INFINITY;
#pragma unroll
    for (int c = 0; c < NCLS; ++c) {
        v[c] = sc[(size_t)c * NPRIOR];
        mx = fmaxf(mx, v[c]);
    }
    float sum = 0.f;
#pragma unroll
    for (int c = 0; c < NCLS; ++c) {
        v[c] = expf(__fsub_rn(v[c], mx));
        sum = __fadd_rn(sum, v[c]);
    }

    // ---- scatter candidates (classes 1..80) ----
    unsigned int invn = 0xFFFFFFFFu - (unsigned int)n;
#pragma unroll
    for (int c = 1; c < NCLS; ++c) {
        float p = __fdiv_rn(v[c], sum);
        if (p > CONF_T) {
            unsigned int idx = (unsigned int)b * NCLS_OUT + (unsigned int)(c - 1);
            unsigned int pos = atomicAdd(&counters[idx], 1u);
            if (pos < CAND_CAP) {
                cand_g[(size_t)idx * CAND_CAP + pos] =
                    ((unsigned long long)__float_as_uint(p) << 32) | (unsigned long long)invn;
            }
        }
    }
}

// ---------------------------------------------------------------------------
// Bitonic sort (descending) on P (power of 2) u64 keys in LDS, 256 threads.
// ---------------------------------------------------------------------------
__device__ inline void bitonic_desc(unsigned long long* keys, int P, int tid) {
    for (int k = 2; k <= P; k <<= 1) {
        for (int j = k >> 1; j > 0; j >>= 1) {
            for (int i = tid; i < P; i += 256) {
                int l = i ^ j;
                if (l > i) {
                    unsigned long long a = keys[i], b = keys[l];
                    bool desc = ((i & k) == 0);
                    if (desc ? (a < b) : (a > b)) {
                        keys[i] = b;
                        keys[l] = a;
                    }
                }
            }
            __syncthreads();
        }
    }
}

// ---------------------------------------------------------------------------
// Kernel B: per (b, class): sort candidates (desc score, asc index), take top
// 200, sequential-NMS via row bitmasks, write per-class scores & boxes.
// ---------------------------------------------------------------------------
__global__ __launch_bounds__(256) void nms_class(
    const unsigned int* __restrict__ counters,
    const unsigned long long* __restrict__ cand_g,
    const float* __restrict__ boxes_ltrb,
    float* __restrict__ cls_scores,  // (B,80,200)
    float* __restrict__ cls_boxes)   // (B,80,200,4)
{
    __shared__ unsigned long long cand[CAND_CAP];
    __shared__ float sbox[NDET][4];
    __shared__ float sscore[NDET];
    __shared__ unsigned long long rowm[NDET][4];
    __shared__ unsigned long long keepw[4];

    int tid = threadIdx.x;
    int b = blockIdx.y;
    int bc = b * NCLS_OUT + blockIdx.x;

    unsigned int cntu = counters[bc];
    int cnt = (cntu > CAND_CAP) ? CAND_CAP : (int)cntu;

    int P = 256;
    while (P < cnt) P <<= 1;  // <= CAND_CAP

    for (int i = tid; i < P; i += 256)
        cand[i] = (i < cnt) ? cand_g[(size_t)bc * CAND_CAP + i] : 0ull;
    __syncthreads();

    bitonic_desc(cand, P, tid);

    int m = cnt < NDET ? cnt : NDET;
    if (tid < m) {
        unsigned long long key = cand[tid];
        unsigned int n = 0xFFFFFFFFu - (unsigned int)(key & 0xFFFFFFFFull);
        sscore[tid] = __uint_as_float((unsigned int)(key >> 32));
        float4 bx = ((const float4*)boxes_ltrb)[(size_t)b * NPRIOR + n];
        sbox[tid][0] = bx.x;
        sbox[tid][1] = bx.y;
        sbox[tid][2] = bx.z;
        sbox[tid][3] = bx.w;
    }
    __syncthreads();

    // row bitmasks: row i -> bits j>i with iou(i,j) > IOU_T
    if (tid < m) {
        float l0 = sbox[tid][0], t0 = sbox[tid][1], r0 = sbox[tid][2], b0 = sbox[tid][3];
        float area0 = __fmul_rn(__fsub_rn(r0, l0), __fsub_rn(b0, t0));
        unsigned long long w0 = 0, w1 = 0, w2 = 0, w3 = 0;
        for (int j = tid + 1; j < m; ++j) {
            float lj = sbox[j][0], tj = sbox[j][1], rj = sbox[j][2], bj = sbox[j][3];
            float ltx = fmaxf(l0, lj), lty = fmaxf(t0, tj);
            float rbx = fminf(r0, rj), rby = fminf(b0, bj);
            float iw = fmaxf(__fsub_rn(rbx, ltx), 0.f);
            float ih = fmaxf(__fsub_rn(rby, lty), 0.f);
            float inter = __fmul_rn(iw, ih);
            float areaj = __fmul_rn(__fsub_rn(rj, lj), __fsub_rn(bj, tj));
            float den = __fsub_rn(__fadd_rn(area0, areaj), inter);
            float iou = __fdiv_rn(inter, den);
            if (iou > IOU_T) {
                if (j < 64) w0 |= 1ull << j;
                else if (j < 128) w1 |= 1ull << (j - 64);
                else if (j < 192) w2 |= 1ull << (j - 128);
                else w3 |= 1ull << (j - 192);
            }
        }
        rowm[tid][0] = w0;
        rowm[tid][1] = w1;
        rowm[tid][2] = w2;
        rowm[tid][3] = w3;
    }
    __syncthreads();

    if (tid == 0) {
        auto maskf = [](int t) -> unsigned long long {
            if (t <= 0) return 0ull;
            if (t >= 64) return ~0ull;
            return (1ull << t) - 1ull;
        };
        unsigned long long k0 = maskf(m), k1 = maskf(m - 64), k2 = maskf(m - 128), k3 = maskf(m - 192);
        for (int i = 0; i < m; ++i) {
            unsigned long long cur = (i < 64) ? k0 : (i < 128) ? k1 : (i < 192) ? k2 : k3;
            if ((cur >> (i & 63)) & 1ull) {
                k0 &= ~rowm[i][0];
                k1 &= ~rowm[i][1];
                k2 &= ~rowm[i][2];
                k3 &= ~rowm[i][3];
            }
        }
        keepw[0] = k0; keepw[1] = k1; keepw[2] = k2; keepw[3] = k3;
    }
    __syncthreads();

    if (tid < NDET) {
        float s = -1.0f;
        if (tid < m && ((keepw[tid >> 6] >> (tid & 63)) & 1ull)) s = sscore[tid];
        cls_scores[(size_t)bc * NDET + tid] = s;
        if (tid < m) {
            float4 bx;
            bx.x = sbox[tid][0]; bx.y = sbox[tid][1];
            bx.z = sbox[tid][2]; bx.w = sbox[tid][3];
            ((float4*)cls_boxes)[(size_t)bc * NDET + tid] = bx;
        }
    }
}

// ---------------------------------------------------------------------------
// Kernel C1: per (group of 16 classes, batch): collect valid (score>CONF_T),
// sort desc, emit top-200 keys (pad 0). Exact: any global-top-200 element is
// within its group's top-200.
// ---------------------------------------------------------------------------
__global__ __launch_bounds__(256) void topk_group(
    const float* __restrict__ cls_scores,
    unsigned long long* __restrict__ grp_keys) // (B, NGRP, 200)
{
    __shared__ unsigned long long keys[4096];
    __shared__ unsigned int cnt_s;

    int tid = threadIdx.x;
    int g = blockIdx.x, b = blockIdx.y;
    if (tid == 0) cnt_s = 0;
    __syncthreads();

    int base_e = g * GRP * NDET;
    const float* sp = cls_scores + (size_t)b * NCLS_OUT * NDET + base_e;
    for (int i = tid; i < GRP * NDET; i += 256) {
        float s = sp[i];
        if (s > CONF_T) {
            unsigned int pos = atomicAdd(&cnt_s, 1u);
            unsigned int e = (unsigned int)(base_e + i);
            keys[pos] = ((unsigned long long)__float_as_uint(s) << 32) |
                        (unsigned long long)(0xFFFFFFFFu - e);
        }
    }
    __syncthreads();
    int cnt = (int)cnt_s;  // <= 3200
    int P = 256;
    while (P < cnt) P <<= 1;  // <= 4096
    for (int i = tid; i < P; i += 256)
        if (i >= cnt) keys[i] = 0ull;
    __syncthreads();

    bitonic_desc(keys, P, tid);

    if (tid < NDET)
        grp_keys[((size_t)b * NGRP + g) * NDET + tid] = (tid < cnt) ? keys[tid] : 0ull;
}

// ---------------------------------------------------------------------------
// Kernel C2: per batch: merge 5*200 group keys, sort, emit final top-200.
// ---------------------------------------------------------------------------
__global__ __launch_bounds__(256) void final_topk(
    const unsigned long long* __restrict__ grp_keys,
    const float* __restrict__ cls_boxes,
    float* __restrict__ out)
{
    __shared__ unsigned long long keys[1024];
    __shared__ unsigned int cnt_s;

    int tid = threadIdx.x, b = blockIdx.x;
    if (tid == 0) cnt_s = 0;
    __syncthreads();

    for (int i = tid; i < NGRP * NDET; i += 256) {
        unsigned long long k = grp_keys[(size_t)b * NGRP * NDET + i];
        if (k != 0ull) keys[atomicAdd(&cnt_s, 1u)] = k;
    }
    __syncthreads();
    int cnt = (int)cnt_s;  // <= 1000
    int P = 256;
    while (P < cnt) P <<= 1;  // <= 1024
    for (int i = tid; i < P; i += 256)
        if (i >= cnt) keys[i] = 0ull;
    __syncthreads();

    bitonic_desc(keys, P, tid);

    if (tid < NDET) {
        float4 bx = make_float4(0.f, 0.f, 0.f, 0.f);
        float lab = 0.f, sc = 0.f;
        if (tid < cnt) {
            unsigned long long k = keys[tid];
            unsigned int e = 0xFFFFFFFFu - (unsigned int)(k & 0xFFFFFFFFull);
            sc = __uint_as_float((unsigned int)(k >> 32));
            unsigned int c0 = e / NDET;
            bx = ((const float4*)cls_boxes)[(size_t)b * NCLS_OUT * NDET + e];
            lab = (float)(c0 + 1);
        }
        float* fb = out;                                // (B,200,4)
        float* fl = out + (size_t)BATCH * NDET * 4;     // (B,200)
        float* fs = fl + (size_t)BATCH * NDET;          // (B,200)
        ((float4*)fb)[b * NDET + tid] = bx;
        fl[b * NDET + tid] = lab;
        fs[b * NDET + tid] = sc;
    }
}

// ---------------------------------------------------------------------------
extern "C" void kernel_launch(void* const* d_in, const int* in_sizes, int n_in,
                              void* d_out, int out_size, void* d_ws, size_t ws_size,
                              hipStream_t stream) {
    const float* bboxes = (const float*)d_in[0];
    const float* scores = (const float*)d_in[1];
    const float* sxy    = (const float*)d_in[2];
    const float* swh    = (const float*)d_in[3];
    const float* dbx    = (const float*)d_in[4];
    float* out = (float*)d_out;

    char* ws = (char*)d_ws;
    size_t off = 0;
    auto alloc = [&](size_t bytes) -> char* {
        char* p = ws + off;
        off += (bytes + 255) & ~(size_t)255;
        return p;
    };
    float* boxes_ltrb            = (float*)alloc((size_t)BATCH * NPRIOR * 4 * 4);
    unsigned int* counters       = (unsigned int*)alloc((size_t)BATCH * NCLS_OUT * 4);
    unsigned long long* cand_g   = (unsigned long long*)alloc((size_t)BATCH * NCLS_OUT * CAND_CAP * 8);
    float* cls_scores            = (float*)alloc((size_t)BATCH * NCLS_OUT * NDET * 4);
    float* cls_boxes             = (float*)alloc((size_t)BATCH * NCLS_OUT * NDET * 4 * 4);
    unsigned long long* grp_keys = (unsigned long long*)alloc((size_t)BATCH * NGRP * NDET * 8);

    int ncounters = BATCH * NCLS_OUT;
    zero_counters<<<(ncounters + 255) / 256, 256, 0, stream>>>(counters, ncounters);

    dim3 gridA((NPRIOR + 255) / 256, BATCH);
    decode_softmax_scatter<<<gridA, 256, 0, stream>>>(
        bboxes, scores, sxy, swh, dbx, boxes_ltrb, counters, cand_g);

    dim3 gridB(NCLS_OUT, BATCH);
    nms_class<<<gridB, 256, 0, stream>>>(counters, cand_g, boxes_ltrb, cls_scores, cls_boxes);

    dim3 gridC1(NGRP, BATCH);
    topk_group<<<gridC1, 256, 0, stream>>>(cls_scores, grp_keys);

    final_topk<<<BATCH, 256, 0, stream>>>(grp_keys, cls_boxes, out);
}